// Round 10
// baseline (821.446 us; speedup 1.0000x reference)
//
#include <hip/hip_runtime.h>
#include <math.h>

// QuaternionAttention B=4, L=S=2048, H=8, E=64, M=4 (fp32 in/out).
// Round 18: 2-blocks-per-CU occupancy, on the round-17 base (121.3us:
// QBLK=256/NTH=512, in-register P via sigma-QK, krot dbuf, f(k) swizzle).
// r17 counters: MFMA 30.6 / VALU 43.8 / conflicts 15% -> combined 74%, but
// only 2 waves/SIMD (80KB LDS = 1 block/CU). This round shaves LDS to 72KB
// so 2 blocks (4 waves/SIMD) co-reside and cross-block waves hide each
// other's VALU/MFMA/conflict time:
//   - vts single-buffered; tile split into 2 barrier intervals:
//     A: QK | BUILDK(ti+1->buf^1) | softmax | PV      (reads vts(ti))
//     B: VBUILD(ti+1) | LOAD(ti+2)                    (writes vts)
//   - q-trig computed per-lane into registers (qtrc/qtrs LDS deleted);
//     qstage overlay (69.6KB) fits under the 73728B total.
//   - __launch_bounds__(512,4) pins VGPR<=128 (exactly current usage).
// All arithmetic bit-identical to round 17 (same swizzles, same order of
// operations within each computation).

#define B_ 4
#define L_ 2048
#define S_ 2048
#define H_ 8
#define E_ 64
#define M_ 4
#define QBLK 256
#define NTH 512
#define NTILES 32

#define KROT_OFF 0          // 2 x 32KB
#define VTS_OFF  65536      // 1 x 8KB
#define SMEM_BYTES 73728

typedef _Float16 f16x4 __attribute__((ext_vector_type(4)));
typedef _Float16 f16x8 __attribute__((ext_vector_type(8)));
typedef __fp16 fp16x2 __attribute__((ext_vector_type(2)));   // cvt_pkrtz return type
typedef float f32x4 __attribute__((ext_vector_type(4)));

union H4U { f16x4 h; fp16x2 p[2]; };
union H8U { f16x8 h; fp16x2 p[4]; };
union F4U { float4 v; float f[4]; };

#if __has_builtin(__builtin_amdgcn_sinf) && __has_builtin(__builtin_amdgcn_cosf)
#define FSINCOS(ang, s, c) do { float _rv = (ang) * 0.15915494309189535f; \
    (s) = __builtin_amdgcn_sinf(_rv); (c) = __builtin_amdgcn_cosf(_rv); } while (0)
#else
#define FSINCOS(ang, s, c) __sincosf((ang), &(s), &(c))
#endif

__device__ __forceinline__ f16x4 cvt4(float x, float y, float z, float w) {
    H4U r;
    r.p[0] = __builtin_amdgcn_cvt_pkrtz(x, y);
    r.p[1] = __builtin_amdgcn_cvt_pkrtz(z, w);
    return r.h;
}
__device__ __forceinline__ f16x8 cvt8(const float* v) {
    H8U r;
#pragma unroll
    for (int i = 0; i < 4; ++i) r.p[i] = __builtin_amdgcn_cvt_pkrtz(v[2 * i], v[2 * i + 1]);
    return r.h;
}

__global__ __launch_bounds__(NTH, 4)
void qattn11(const float* __restrict__ qp, const float* __restrict__ kp,
             const float* __restrict__ vp,
             const float* __restrict__ qo, const float* __restrict__ qt,
             const float* __restrict__ ko, const float* __restrict__ ktt,
             float* __restrict__ out)
{
    // XCD-chunked swizzle (256 blocks, bijective): each XCD gets 32
    // consecutive nl = 4 (b,h) groups.
    const int bid0 = blockIdx.x;                  // 0..255
    const int nl = (bid0 & 7) * 32 + (bid0 >> 3);
    const int l0 = (nl & 7) * QBLK;
    const int h  = (nl >> 3) & 7;
    const int b  = nl >> 6;
    const int t  = threadIdx.x;
    const int wv   = t >> 6;                      // 0..7
    const int lane = t & 63;
    const int quad = lane >> 4;
    const int nn   = lane & 15;

    __shared__ __align__(16) unsigned char smem[SMEM_BYTES];
    float (*qstage)[68] = reinterpret_cast<float (*)[68]>(smem);   // 69.6KB init overlay
    _Float16 (*vts)[64] = reinterpret_cast<_Float16 (*)[64]>(smem + VTS_OFF);

    const float* kb0 = kp  + ((size_t)((b * S_) * H_ + h)) * E_;
    const float* vb0 = vp  + ((size_t)((b * S_) * H_ + h)) * E_;
    const float* kob = ko  + ((size_t)((b * S_) * H_ + h)) * M_;
    const float* ktb = ktt + ((size_t)((b * S_) * H_ + h)) * M_;

    // K_rot build roles: 8 threads per key = 4 components x 2 e-halves
    const int key_r = t >> 3;       // 0..63
    const int ccr   = (t >> 1) & 3; // component
    const int eh    = t & 1;        // e-half within component
    const int swz   = (key_r & 3) | ((key_r >> 1) & 4);   // f(k): bit2 from k's bit3
    // V^T roles (upper 256 threads)
    const int tt = t & 255;
    const int kg = tt >> 4;         // key group (4 keys)
    const int eg = tt & 15;         // e group (4 e's)

    // ---- register pipeline: next tile's K slices, trig, V rows ----
    F4U kA[2], kB[2], omR, thR, vv[4];
    auto LOAD = [&](int s0) {
        const float* kr = kb0 + (size_t)(s0 + key_r) * (H_ * E_);
        kA[0].v = *(const float4*)(kr + ccr * 16 + eh * 8);            // a = k[cc]
        kA[1].v = *(const float4*)(kr + ccr * 16 + eh * 8 + 4);
        kB[0].v = *(const float4*)(kr + (ccr ^ 2) * 16 + eh * 8);      // b = k[cc^2]
        kB[1].v = *(const float4*)(kr + (ccr ^ 2) * 16 + eh * 8 + 4);
        omR.v = *(const float4*)(kob + (size_t)(s0 + key_r) * (H_ * M_));
        thR.v = *(const float4*)(ktb + (size_t)(s0 + key_r) * (H_ * M_));
        if (t >= 256) {
#pragma unroll
            for (int j = 0; j < 4; ++j)
                vv[j].v = *(const float4*)(vb0 + (size_t)(s0 + kg * 4 + j) * (H_ * E_) + eg * 4);
        }
    };

    // ---- K_rot build into the given krot buffer (K signs: c0:-,c1:-,c2:+,c3:+) ----
    auto BUILDK = [&](int s0, int koff) {
        _Float16 (*krw)[256] = reinterpret_cast<_Float16 (*)[256]>(smem + koff);
        float af[8], bf[8];
#pragma unroll
        for (int i2 = 0; i2 < 4; ++i2) {
            af[i2]     = kA[0].f[i2];
            af[4 + i2] = kA[1].f[i2];
            bf[i2]     = kB[0].f[i2];
            bf[4 + i2] = kB[1].f[i2];
        }
        float posk = (float)(s0 + key_r) * (1.0f / S_);
        float kcv[4], ksv[4];
#pragma unroll
        for (int m = 0; m < 4; ++m) {
            float ang = fmaf(omR.f[m], posk, thR.f[m]);
            FSINCOS(ang, ksv[m], kcv[m]);
        }
        const float sgn = (ccr >= 2) ? 1.f : -1.f;
#pragma unroll
        for (int m = 0; m < 4; ++m) {
            float cm = kcv[m], sm = ksv[m] * sgn;
            float vals[8];
#pragma unroll
            for (int i = 0; i < 8; ++i)
                vals[i] = fmaf(bf[i], sm, af[i] * cm);
            int ch = (m * 8) | ((ccr * 2 + eh) ^ swz);
            *(f16x8*)&krw[key_r][ch * 8] = cvt8(vals);
        }
    };
    // ---- V^T staging (upper 256 threads; 4x4 register transpose, s(row) swizzle) ----
    auto VBUILD = [&]() {
        if (t >= 256) {
#pragma unroll
            for (int e = 0; e < 4; ++e) {
                int row = eg * 4 + e;
                int srow = ((row & 7) ^ (row >> 3)) & 7;
                int ch = (kg >> 1) ^ srow;
                *(f16x4*)&vts[row][ch * 8 + (kg & 1) * 4] =
                    cvt4(vv[0].f[e], vv[1].f[e], vv[2].f[e], vv[3].f[e]);
            }
        }
    };

    LOAD(0);   // tile-0 loads fly under Q_rot construction

    // ---- build Q_rot A-fragments once per block (scale log2(e)/32 folded) ----
    // Two sets per wave: set s covers rows wv*32 + s*16 + (0..15).
    f16x8 qa[2][8];
    {
        const float* qb = qp + ((size_t)((b * L_ + l0) * H_ + h)) * E_;
#pragma unroll
        for (int i = 0; i < 8; ++i) {
            int idx = t + NTH * i;                 // 0..4095
            int row = idx >> 4, c16 = idx & 15;
            *(float4*)&qstage[row][c16 * 4] =
                *(const float4*)(qb + (size_t)row * (H_ * E_) + c16 * 4);
        }
        __syncthreads();
#pragma unroll
        for (int set = 0; set < 2; ++set) {
            const int row = wv * 32 + set * 16 + nn;   // A-frag row = lane&15
            // per-lane q-trig (4 quads redundant; init-only)
            F4U qc4, qs4;
            {
                size_t off = (size_t)((b * L_ + l0 + row) * H_ + h) * M_;
                F4U qov, qtv;
                qov.v = *(const float4*)(qo + off);
                qtv.v = *(const float4*)(qt + off);
                float pos = (float)(l0 + row) * (1.0f / L_);
#pragma unroll
                for (int m = 0; m < 4; ++m) {
                    float ang = fmaf(qov.f[m], pos, qtv.f[m]);
                    FSINCOS(ang, qs4.f[m], qc4.f[m]);
                }
            }
            const int i0 = (quad & 1) * 8;
            float sl0[8], sl1[8], sl2[8], sl3[8];
            *(float4*)&sl0[0] = *(float4*)&qstage[row][ 0 + i0];
            *(float4*)&sl0[4] = *(float4*)&qstage[row][ 4 + i0];
            *(float4*)&sl1[0] = *(float4*)&qstage[row][16 + i0];
            *(float4*)&sl1[4] = *(float4*)&qstage[row][20 + i0];
            *(float4*)&sl2[0] = *(float4*)&qstage[row][32 + i0];
            *(float4*)&sl2[4] = *(float4*)&qstage[row][36 + i0];
            *(float4*)&sl3[0] = *(float4*)&qstage[row][48 + i0];
            *(float4*)&sl3[4] = *(float4*)&qstage[row][52 + i0];
            // even ks -> c = quad>>1 (0 or 1); odd ks -> c+2.
            // Q signs: c0:-, c1:+, c2:+, c3:-   (b = q[c^1])
            const bool hiC = (quad & 2) != 0;
            float aE[8], bE[8], aO[8], bO[8];
#pragma unroll
            for (int j = 0; j < 8; ++j) {
                aE[j] = hiC ? sl1[j] : sl0[j];
                bE[j] = hiC ? sl0[j] : sl1[j];
                aO[j] = hiC ? sl3[j] : sl2[j];
                bO[j] = hiC ? sl2[j] : sl3[j];
            }
            const float SC = 0.04508422017f;   // log2(e)/32
#pragma unroll
            for (int m = 0; m < 4; ++m) {
                float cm = qc4.f[m] * SC;
                float sm = qs4.f[m] * SC;
                float sE = hiC ? sm : -sm;     // c=1:+  c=0:-
                float vE[8], vO[8];
#pragma unroll
                for (int j = 0; j < 8; ++j) {
                    vE[j] = fmaf(bE[j], sE, aE[j] * cm);
                    vO[j] = fmaf(bO[j], -sE, aO[j] * cm);   // c=2:+  c=3:-
                }
                qa[set][2 * m]     = cvt8(vE);
                qa[set][2 * m + 1] = cvt8(vO);
            }
        }
        __syncthreads();   // qstage overlay now free
    }

    f32x4 Oacc[2][4] = {{{0,0,0,0},{0,0,0,0},{0,0,0,0},{0,0,0,0}},
                        {{0,0,0,0},{0,0,0,0},{0,0,0,0},{0,0,0,0}}};
    float mrow[2] = {-1e30f, -1e30f};   // per set: lane's Q-row = wv*32+set*16+nn
    float lrow[2] = {0.f, 0.f};

    // sigma-permuted QK row base: lane nn reads krot row (nn>>2)*8 + (nn&3)
    // (+ ks2*32 + hf*4), so D-slot (quad, r) holds key ks2*32+quad*8+hf*4+r.
    const int sigrow = ((nn >> 2) << 3) + (nn & 3);
    const int xr = nn & 7;   // = f(keyb) for every (ks2,hf): full 3-bit spread

    // ---- prologue: tile 0 built, tile 1 loads in flight ----
    BUILDK(0, KROT_OFF);
    VBUILD();
    LOAD(64);
    __syncthreads();

    for (int ti = 0; ti < NTILES; ++ti) {
        _Float16 (*krot)[256] = reinterpret_cast<_Float16 (*)[256]>(
            smem + KROT_OFF + (ti & 1) * 32768);

        // ================= phase A =================
        // ---- QK^T swapped + sigma: sc[set][ks2][hf][r] =
        //      score(qrow = wv*32+set*16+nn, key = ks2*32+quad*8+hf*4+r) ----
        float sc[2][2][2][4];
        __builtin_amdgcn_s_setprio(1);
#pragma unroll
        for (int ks2 = 0; ks2 < 2; ++ks2)
#pragma unroll
            for (int hf = 0; hf < 2; ++hf) {
                const int keyb = ks2 * 32 + hf * 4 + sigrow;
                f32x4 acc0 = {0, 0, 0, 0}, acc1 = {0, 0, 0, 0};
#pragma unroll
                for (int ks = 0; ks < 8; ++ks) {
                    f16x8 bK = *(const f16x8*)&krot[keyb][((ks * 4 + quad) ^ xr) * 8];
                    acc0 = __builtin_amdgcn_mfma_f32_16x16x32_f16(bK, qa[0][ks], acc0, 0, 0, 0);
                    acc1 = __builtin_amdgcn_mfma_f32_16x16x32_f16(bK, qa[1][ks], acc1, 0, 0, 0);
                }
#pragma unroll
                for (int r = 0; r < 4; ++r) {
                    sc[0][ks2][hf][r] = acc0[r];
                    sc[1][ks2][hf][r] = acc1[r];
                }
            }
        __builtin_amdgcn_s_setprio(0);

        // ---- K-build tile ti+1 into the other krot buffer ----
        if (ti + 1 < NTILES)
            BUILDK((ti + 1) * 64, KROT_OFF + ((ti + 1) & 1) * 32768);

        // ---- lane-local online softmax (base 2), defer-max THR=8;
        //      P packed in-register straight into PV A-frags ----
        f16x8 pf[2][2];
#pragma unroll
        for (int set = 0; set < 2; ++set) {
            float m0 = fmaxf(fmaxf(sc[set][0][0][0], sc[set][0][0][1]),
                             fmaxf(sc[set][0][0][2], sc[set][0][0][3]));
            float m1 = fmaxf(fmaxf(sc[set][0][1][0], sc[set][0][1][1]),
                             fmaxf(sc[set][0][1][2], sc[set][0][1][3]));
            float m2 = fmaxf(fmaxf(sc[set][1][0][0], sc[set][1][0][1]),
                             fmaxf(sc[set][1][0][2], sc[set][1][0][3]));
            float m3 = fmaxf(fmaxf(sc[set][1][1][0], sc[set][1][1][1]),
                             fmaxf(sc[set][1][1][2], sc[set][1][1][3]));
            float tm = fmaxf(fmaxf(m0, m1), fmaxf(m2, m3));
            tm = fmaxf(tm, __shfl_xor(tm, 16));
            tm = fmaxf(tm, __shfl_xor(tm, 32));   // all quads now hold row-max

            if (__any(tm > mrow[set] + 8.0f)) {   // wave-uniform rescale path
                float mnew  = fmaxf(mrow[set], tm);
                float alpha = __builtin_amdgcn_exp2f(mrow[set] - mnew);
                mrow[set] = mnew;
                lrow[set] *= alpha;
#pragma unroll
                for (int r = 0; r < 4; ++r) {
                    float ar = __shfl(alpha, quad * 4 + r, 64);
                    Oacc[set][0][r] *= ar; Oacc[set][1][r] *= ar;
                    Oacc[set][2][r] *= ar; Oacc[set][3][r] *= ar;
                }
            }

            float p[2][2][4];
#pragma unroll
            for (int ks2 = 0; ks2 < 2; ++ks2)
#pragma unroll
                for (int hf = 0; hf < 2; ++hf)
#pragma unroll
                    for (int r = 0; r < 4; ++r)
                        p[ks2][hf][r] =
                            __builtin_amdgcn_exp2f(sc[set][ks2][hf][r] - mrow[set]);

            float s0s = (p[0][0][0] + p[0][0][1]) + (p[0][0][2] + p[0][0][3]);
            float s1s = (p[0][1][0] + p[0][1][1]) + (p[0][1][2] + p[0][1][3]);
            float s2s = (p[1][0][0] + p[1][0][1]) + (p[1][0][2] + p[1][0][3]);
            float s3s = (p[1][1][0] + p[1][1][1]) + (p[1][1][2] + p[1][1][3]);
            float psum = (s0s + s1s) + (s2s + s3s);
            psum += __shfl_xor(psum, 16);
            psum += __shfl_xor(psum, 32);
            lrow[set] += psum;

            // pack: pf[set][ks2] elems j = hf*4+r  (keys quad*8+j of block ks2)
#pragma unroll
            for (int ks2 = 0; ks2 < 2; ++ks2) {
                H8U pk;
                pk.p[0] = __builtin_amdgcn_cvt_pkrtz(p[ks2][0][0], p[ks2][0][1]);
                pk.p[1] = __builtin_amdgcn_cvt_pkrtz(p[ks2][0][2], p[ks2][0][3]);
                pk.p[2] = __builtin_amdgcn_cvt_pkrtz(p[ks2][1][0], p[ks2][1][1]);
                pk.p[3] = __builtin_amdgcn_cvt_pkrtz(p[ks2][1][2], p[ks2][1][3]);
                pf[set][ks2] = pk.h;
            }
        }

        // ---- PV straight from registers (vf shared across sets) ----
        __builtin_amdgcn_s_setprio(1);
#pragma unroll
        for (int ks2 = 0; ks2 < 2; ++ks2)
#pragma unroll
            for (int et = 0; et < 4; ++et) {
                int e = et * 16 + nn;
                int se = ((nn & 7) ^ ((et * 2 + (nn >> 3)) & 7)) & 7;   // s(e)
                f16x8 vf = *(const f16x8*)&vts[e][((quad + 4 * ks2) ^ se) * 8];
                Oacc[0][et] = __builtin_amdgcn_mfma_f32_16x16x32_f16(pf[0][ks2], vf, Oacc[0][et], 0, 0, 0);
                Oacc[1][et] = __builtin_amdgcn_mfma_f32_16x16x32_f16(pf[1][ks2], vf, Oacc[1][et], 0, 0, 0);
            }
        __builtin_amdgcn_s_setprio(0);
        __syncthreads();   // all PV vts reads + krot(nxt) writes done

        // ================= phase B =================
        if (ti + 1 < NTILES) {
            VBUILD();                         // vts(ti+1) from vv = LOAD(ti+1)
            if (ti + 2 < NTILES) LOAD((ti + 2) * 64);
        }
        __syncthreads();   // vts(ti+1) visible to all waves' PV next iter
    }

    // ---- epilogue ----
    float* ob = out + ((size_t)((b * L_ + l0) * H_ + h)) * E_;
#pragma unroll
    for (int set = 0; set < 2; ++set)
#pragma unroll
        for (int r = 0; r < 4; ++r) {
            float lr = __shfl(lrow[set], quad * 4 + r, 64);
            float inv = 1.0f / lr;
            int row = wv * 32 + set * 16 + quad * 4 + r;   // 0..255
#pragma unroll
            for (int et = 0; et < 4; ++et)
                ob[(size_t)row * (H_ * E_) + et * 16 + nn] = Oacc[set][et][r] * inv;
        }
}

extern "C" void kernel_launch(void* const* d_in, const int* in_sizes, int n_in,
                              void* d_out, int out_size, void* d_ws, size_t ws_size,
                              hipStream_t stream) {
    const float* qp = (const float*)d_in[0];
    const float* kp = (const float*)d_in[1];
    const float* vp = (const float*)d_in[2];
    const float* qo = (const float*)d_in[3];
    const float* qt = (const float*)d_in[4];
    const float* ko = (const float*)d_in[5];
    const float* kt = (const float*)d_in[6];
    float* out = (float*)d_out;

    qattn11<<<dim3(B_ * H_ * (L_ / QBLK)), dim3(NTH), 0, stream>>>(
        qp, kp, vp, qo, qt, ko, kt, out);
}

// Round 11
// 191.938 us; speedup vs baseline: 4.2798x; 4.2798x over previous
//
#include <hip/hip_runtime.h>
#include <math.h>

// QuaternionAttention B=4, L=S=2048, H=8, E=64, M=4 (fp32 in/out).
// Round 19 = round 18 with the launch_bounds clamp fixed. Round 18 (750us!)
// proved hipcc treats __launch_bounds__'s 2nd arg as min BLOCKS/CU for
// 512-thread blocks: (512,4) forced VGPR<=64 -> 860MB scratch spill
// (WRITE_SIZE 16MB->860MB, FETCH 29MB->1.17GB, VGPR_Count 64). Structure
// itself passed and is kept bit-identical:
//   - LDS 72KB (krot dbuf 2x32KB | vts single 8KB) -> 2 blocks/CU fit
//     (147456 <= 163840), 4 waves/SIMD at VGPR<=128.
//   - tile = 2 barrier intervals: A: QK | BUILDK(ti+1) | softmax | PV;
//     B: VBUILD(ti+1) | LOAD(ti+2).
//   - in-register P via sigma-QK, f(k) krot swizzle, s(row) vts swizzle,
//     defer-max, raw v_sin/v_cos, per-lane q-trig.
// Now __launch_bounds__(512,2): 2 blocks x 8 waves = 16 waves/CU = 4/SIMD
// -> VGPR cap 128 (the r17 natural allocation). Canary: VGPR must be ~128
// and WRITE_SIZE 16384; dur ~95-110us if 2-block co-residency engages.

#define B_ 4
#define L_ 2048
#define S_ 2048
#define H_ 8
#define E_ 64
#define M_ 4
#define QBLK 256
#define NTH 512
#define NTILES 32

#define KROT_OFF 0          // 2 x 32KB
#define VTS_OFF  65536      // 1 x 8KB
#define SMEM_BYTES 73728

typedef _Float16 f16x4 __attribute__((ext_vector_type(4)));
typedef _Float16 f16x8 __attribute__((ext_vector_type(8)));
typedef __fp16 fp16x2 __attribute__((ext_vector_type(2)));   // cvt_pkrtz return type
typedef float f32x4 __attribute__((ext_vector_type(4)));

union H4U { f16x4 h; fp16x2 p[2]; };
union H8U { f16x8 h; fp16x2 p[4]; };
union F4U { float4 v; float f[4]; };

#if __has_builtin(__builtin_amdgcn_sinf) && __has_builtin(__builtin_amdgcn_cosf)
#define FSINCOS(ang, s, c) do { float _rv = (ang) * 0.15915494309189535f; \
    (s) = __builtin_amdgcn_sinf(_rv); (c) = __builtin_amdgcn_cosf(_rv); } while (0)
#else
#define FSINCOS(ang, s, c) __sincosf((ang), &(s), &(c))
#endif

__device__ __forceinline__ f16x4 cvt4(float x, float y, float z, float w) {
    H4U r;
    r.p[0] = __builtin_amdgcn_cvt_pkrtz(x, y);
    r.p[1] = __builtin_amdgcn_cvt_pkrtz(z, w);
    return r.h;
}
__device__ __forceinline__ f16x8 cvt8(const float* v) {
    H8U r;
#pragma unroll
    for (int i = 0; i < 4; ++i) r.p[i] = __builtin_amdgcn_cvt_pkrtz(v[2 * i], v[2 * i + 1]);
    return r.h;
}

__global__ __launch_bounds__(NTH, 2)
void qattn12(const float* __restrict__ qp, const float* __restrict__ kp,
             const float* __restrict__ vp,
             const float* __restrict__ qo, const float* __restrict__ qt,
             const float* __restrict__ ko, const float* __restrict__ ktt,
             float* __restrict__ out)
{
    // XCD-chunked swizzle (256 blocks, bijective): each XCD gets 32
    // consecutive nl = 4 (b,h) groups.
    const int bid0 = blockIdx.x;                  // 0..255
    const int nl = (bid0 & 7) * 32 + (bid0 >> 3);
    const int l0 = (nl & 7) * QBLK;
    const int h  = (nl >> 3) & 7;
    const int b  = nl >> 6;
    const int t  = threadIdx.x;
    const int wv   = t >> 6;                      // 0..7
    const int lane = t & 63;
    const int quad = lane >> 4;
    const int nn   = lane & 15;

    __shared__ __align__(16) unsigned char smem[SMEM_BYTES];
    float (*qstage)[68] = reinterpret_cast<float (*)[68]>(smem);   // 69.6KB init overlay
    _Float16 (*vts)[64] = reinterpret_cast<_Float16 (*)[64]>(smem + VTS_OFF);

    const float* kb0 = kp  + ((size_t)((b * S_) * H_ + h)) * E_;
    const float* vb0 = vp  + ((size_t)((b * S_) * H_ + h)) * E_;
    const float* kob = ko  + ((size_t)((b * S_) * H_ + h)) * M_;
    const float* ktb = ktt + ((size_t)((b * S_) * H_ + h)) * M_;

    // K_rot build roles: 8 threads per key = 4 components x 2 e-halves
    const int key_r = t >> 3;       // 0..63
    const int ccr   = (t >> 1) & 3; // component
    const int eh    = t & 1;        // e-half within component
    const int swz   = (key_r & 3) | ((key_r >> 1) & 4);   // f(k): bit2 from k's bit3
    // V^T roles (upper 256 threads)
    const int tt = t & 255;
    const int kg = tt >> 4;         // key group (4 keys)
    const int eg = tt & 15;         // e group (4 e's)

    // ---- register pipeline: next tile's K slices, trig, V rows ----
    F4U kA[2], kB[2], omR, thR, vv[4];
    auto LOAD = [&](int s0) {
        const float* kr = kb0 + (size_t)(s0 + key_r) * (H_ * E_);
        kA[0].v = *(const float4*)(kr + ccr * 16 + eh * 8);            // a = k[cc]
        kA[1].v = *(const float4*)(kr + ccr * 16 + eh * 8 + 4);
        kB[0].v = *(const float4*)(kr + (ccr ^ 2) * 16 + eh * 8);      // b = k[cc^2]
        kB[1].v = *(const float4*)(kr + (ccr ^ 2) * 16 + eh * 8 + 4);
        omR.v = *(const float4*)(kob + (size_t)(s0 + key_r) * (H_ * M_));
        thR.v = *(const float4*)(ktb + (size_t)(s0 + key_r) * (H_ * M_));
        if (t >= 256) {
#pragma unroll
            for (int j = 0; j < 4; ++j)
                vv[j].v = *(const float4*)(vb0 + (size_t)(s0 + kg * 4 + j) * (H_ * E_) + eg * 4);
        }
    };

    // ---- K_rot build into the given krot buffer (K signs: c0:-,c1:-,c2:+,c3:+) ----
    auto BUILDK = [&](int s0, int koff) {
        _Float16 (*krw)[256] = reinterpret_cast<_Float16 (*)[256]>(smem + koff);
        float af[8], bf[8];
#pragma unroll
        for (int i2 = 0; i2 < 4; ++i2) {
            af[i2]     = kA[0].f[i2];
            af[4 + i2] = kA[1].f[i2];
            bf[i2]     = kB[0].f[i2];
            bf[4 + i2] = kB[1].f[i2];
        }
        float posk = (float)(s0 + key_r) * (1.0f / S_);
        float kcv[4], ksv[4];
#pragma unroll
        for (int m = 0; m < 4; ++m) {
            float ang = fmaf(omR.f[m], posk, thR.f[m]);
            FSINCOS(ang, ksv[m], kcv[m]);
        }
        const float sgn = (ccr >= 2) ? 1.f : -1.f;
#pragma unroll
        for (int m = 0; m < 4; ++m) {
            float cm = kcv[m], sm = ksv[m] * sgn;
            float vals[8];
#pragma unroll
            for (int i = 0; i < 8; ++i)
                vals[i] = fmaf(bf[i], sm, af[i] * cm);
            int ch = (m * 8) | ((ccr * 2 + eh) ^ swz);
            *(f16x8*)&krw[key_r][ch * 8] = cvt8(vals);
        }
    };
    // ---- V^T staging (upper 256 threads; 4x4 register transpose, s(row) swizzle) ----
    auto VBUILD = [&]() {
        if (t >= 256) {
#pragma unroll
            for (int e = 0; e < 4; ++e) {
                int row = eg * 4 + e;
                int srow = ((row & 7) ^ (row >> 3)) & 7;
                int ch = (kg >> 1) ^ srow;
                *(f16x4*)&vts[row][ch * 8 + (kg & 1) * 4] =
                    cvt4(vv[0].f[e], vv[1].f[e], vv[2].f[e], vv[3].f[e]);
            }
        }
    };

    LOAD(0);   // tile-0 loads fly under Q_rot construction

    // ---- build Q_rot A-fragments once per block (scale log2(e)/32 folded) ----
    // Two sets per wave: set s covers rows wv*32 + s*16 + (0..15).
    f16x8 qa[2][8];
    {
        const float* qb = qp + ((size_t)((b * L_ + l0) * H_ + h)) * E_;
#pragma unroll
        for (int i = 0; i < 8; ++i) {
            int idx = t + NTH * i;                 // 0..4095
            int row = idx >> 4, c16 = idx & 15;
            *(float4*)&qstage[row][c16 * 4] =
                *(const float4*)(qb + (size_t)row * (H_ * E_) + c16 * 4);
        }
        __syncthreads();
#pragma unroll
        for (int set = 0; set < 2; ++set) {
            const int row = wv * 32 + set * 16 + nn;   // A-frag row = lane&15
            // per-lane q-trig (4 quads redundant; init-only)
            F4U qc4, qs4;
            {
                size_t off = (size_t)((b * L_ + l0 + row) * H_ + h) * M_;
                F4U qov, qtv;
                qov.v = *(const float4*)(qo + off);
                qtv.v = *(const float4*)(qt + off);
                float pos = (float)(l0 + row) * (1.0f / L_);
#pragma unroll
                for (int m = 0; m < 4; ++m) {
                    float ang = fmaf(qov.f[m], pos, qtv.f[m]);
                    FSINCOS(ang, qs4.f[m], qc4.f[m]);
                }
            }
            const int i0 = (quad & 1) * 8;
            float sl0[8], sl1[8], sl2[8], sl3[8];
            *(float4*)&sl0[0] = *(float4*)&qstage[row][ 0 + i0];
            *(float4*)&sl0[4] = *(float4*)&qstage[row][ 4 + i0];
            *(float4*)&sl1[0] = *(float4*)&qstage[row][16 + i0];
            *(float4*)&sl1[4] = *(float4*)&qstage[row][20 + i0];
            *(float4*)&sl2[0] = *(float4*)&qstage[row][32 + i0];
            *(float4*)&sl2[4] = *(float4*)&qstage[row][36 + i0];
            *(float4*)&sl3[0] = *(float4*)&qstage[row][48 + i0];
            *(float4*)&sl3[4] = *(float4*)&qstage[row][52 + i0];
            // even ks -> c = quad>>1 (0 or 1); odd ks -> c+2.
            // Q signs: c0:-, c1:+, c2:+, c3:-   (b = q[c^1])
            const bool hiC = (quad & 2) != 0;
            float aE[8], bE[8], aO[8], bO[8];
#pragma unroll
            for (int j = 0; j < 8; ++j) {
                aE[j] = hiC ? sl1[j] : sl0[j];
                bE[j] = hiC ? sl0[j] : sl1[j];
                aO[j] = hiC ? sl3[j] : sl2[j];
                bO[j] = hiC ? sl2[j] : sl3[j];
            }
            const float SC = 0.04508422017f;   // log2(e)/32
#pragma unroll
            for (int m = 0; m < 4; ++m) {
                float cm = qc4.f[m] * SC;
                float sm = qs4.f[m] * SC;
                float sE = hiC ? sm : -sm;     // c=1:+  c=0:-
                float vE[8], vO[8];
#pragma unroll
                for (int j = 0; j < 8; ++j) {
                    vE[j] = fmaf(bE[j], sE, aE[j] * cm);
                    vO[j] = fmaf(bO[j], -sE, aO[j] * cm);   // c=2:+  c=3:-
                }
                qa[set][2 * m]     = cvt8(vE);
                qa[set][2 * m + 1] = cvt8(vO);
            }
        }
        __syncthreads();   // qstage overlay now free
    }

    f32x4 Oacc[2][4] = {{{0,0,0,0},{0,0,0,0},{0,0,0,0},{0,0,0,0}},
                        {{0,0,0,0},{0,0,0,0},{0,0,0,0},{0,0,0,0}}};
    float mrow[2] = {-1e30f, -1e30f};   // per set: lane's Q-row = wv*32+set*16+nn
    float lrow[2] = {0.f, 0.f};

    // sigma-permuted QK row base: lane nn reads krot row (nn>>2)*8 + (nn&3)
    // (+ ks2*32 + hf*4), so D-slot (quad, r) holds key ks2*32+quad*8+hf*4+r.
    const int sigrow = ((nn >> 2) << 3) + (nn & 3);
    const int xr = nn & 7;   // = f(keyb) for every (ks2,hf): full 3-bit spread

    // ---- prologue: tile 0 built, tile 1 loads in flight ----
    BUILDK(0, KROT_OFF);
    VBUILD();
    LOAD(64);
    __syncthreads();

    for (int ti = 0; ti < NTILES; ++ti) {
        _Float16 (*krot)[256] = reinterpret_cast<_Float16 (*)[256]>(
            smem + KROT_OFF + (ti & 1) * 32768);

        // ================= phase A =================
        // ---- QK^T swapped + sigma: sc[set][ks2][hf][r] =
        //      score(qrow = wv*32+set*16+nn, key = ks2*32+quad*8+hf*4+r) ----
        float sc[2][2][2][4];
        __builtin_amdgcn_s_setprio(1);
#pragma unroll
        for (int ks2 = 0; ks2 < 2; ++ks2)
#pragma unroll
            for (int hf = 0; hf < 2; ++hf) {
                const int keyb = ks2 * 32 + hf * 4 + sigrow;
                f32x4 acc0 = {0, 0, 0, 0}, acc1 = {0, 0, 0, 0};
#pragma unroll
                for (int ks = 0; ks < 8; ++ks) {
                    f16x8 bK = *(const f16x8*)&krot[keyb][((ks * 4 + quad) ^ xr) * 8];
                    acc0 = __builtin_amdgcn_mfma_f32_16x16x32_f16(bK, qa[0][ks], acc0, 0, 0, 0);
                    acc1 = __builtin_amdgcn_mfma_f32_16x16x32_f16(bK, qa[1][ks], acc1, 0, 0, 0);
                }
#pragma unroll
                for (int r = 0; r < 4; ++r) {
                    sc[0][ks2][hf][r] = acc0[r];
                    sc[1][ks2][hf][r] = acc1[r];
                }
            }
        __builtin_amdgcn_s_setprio(0);

        // ---- K-build tile ti+1 into the other krot buffer ----
        if (ti + 1 < NTILES)
            BUILDK((ti + 1) * 64, KROT_OFF + ((ti + 1) & 1) * 32768);

        // ---- lane-local online softmax (base 2), defer-max THR=8;
        //      P packed in-register straight into PV A-frags ----
        f16x8 pf[2][2];
#pragma unroll
        for (int set = 0; set < 2; ++set) {
            float m0 = fmaxf(fmaxf(sc[set][0][0][0], sc[set][0][0][1]),
                             fmaxf(sc[set][0][0][2], sc[set][0][0][3]));
            float m1 = fmaxf(fmaxf(sc[set][0][1][0], sc[set][0][1][1]),
                             fmaxf(sc[set][0][1][2], sc[set][0][1][3]));
            float m2 = fmaxf(fmaxf(sc[set][1][0][0], sc[set][1][0][1]),
                             fmaxf(sc[set][1][0][2], sc[set][1][0][3]));
            float m3 = fmaxf(fmaxf(sc[set][1][1][0], sc[set][1][1][1]),
                             fmaxf(sc[set][1][1][2], sc[set][1][1][3]));
            float tm = fmaxf(fmaxf(m0, m1), fmaxf(m2, m3));
            tm = fmaxf(tm, __shfl_xor(tm, 16));
            tm = fmaxf(tm, __shfl_xor(tm, 32));   // all quads now hold row-max

            if (__any(tm > mrow[set] + 8.0f)) {   // wave-uniform rescale path
                float mnew  = fmaxf(mrow[set], tm);
                float alpha = __builtin_amdgcn_exp2f(mrow[set] - mnew);
                mrow[set] = mnew;
                lrow[set] *= alpha;
#pragma unroll
                for (int r = 0; r < 4; ++r) {
                    float ar = __shfl(alpha, quad * 4 + r, 64);
                    Oacc[set][0][r] *= ar; Oacc[set][1][r] *= ar;
                    Oacc[set][2][r] *= ar; Oacc[set][3][r] *= ar;
                }
            }

            float p[2][2][4];
#pragma unroll
            for (int ks2 = 0; ks2 < 2; ++ks2)
#pragma unroll
                for (int hf = 0; hf < 2; ++hf)
#pragma unroll
                    for (int r = 0; r < 4; ++r)
                        p[ks2][hf][r] =
                            __builtin_amdgcn_exp2f(sc[set][ks2][hf][r] - mrow[set]);

            float s0s = (p[0][0][0] + p[0][0][1]) + (p[0][0][2] + p[0][0][3]);
            float s1s = (p[0][1][0] + p[0][1][1]) + (p[0][1][2] + p[0][1][3]);
            float s2s = (p[1][0][0] + p[1][0][1]) + (p[1][0][2] + p[1][0][3]);
            float s3s = (p[1][1][0] + p[1][1][1]) + (p[1][1][2] + p[1][1][3]);
            float psum = (s0s + s1s) + (s2s + s3s);
            psum += __shfl_xor(psum, 16);
            psum += __shfl_xor(psum, 32);
            lrow[set] += psum;

            // pack: pf[set][ks2] elems j = hf*4+r  (keys quad*8+j of block ks2)
#pragma unroll
            for (int ks2 = 0; ks2 < 2; ++ks2) {
                H8U pk;
                pk.p[0] = __builtin_amdgcn_cvt_pkrtz(p[ks2][0][0], p[ks2][0][1]);
                pk.p[1] = __builtin_amdgcn_cvt_pkrtz(p[ks2][0][2], p[ks2][0][3]);
                pk.p[2] = __builtin_amdgcn_cvt_pkrtz(p[ks2][1][0], p[ks2][1][1]);
                pk.p[3] = __builtin_amdgcn_cvt_pkrtz(p[ks2][1][2], p[ks2][1][3]);
                pf[set][ks2] = pk.h;
            }
        }

        // ---- PV straight from registers (vf shared across sets) ----
        __builtin_amdgcn_s_setprio(1);
#pragma unroll
        for (int ks2 = 0; ks2 < 2; ++ks2)
#pragma unroll
            for (int et = 0; et < 4; ++et) {
                int e = et * 16 + nn;
                int se = ((nn & 7) ^ ((et * 2 + (nn >> 3)) & 7)) & 7;   // s(e)
                f16x8 vf = *(const f16x8*)&vts[e][((quad + 4 * ks2) ^ se) * 8];
                Oacc[0][et] = __builtin_amdgcn_mfma_f32_16x16x32_f16(pf[0][ks2], vf, Oacc[0][et], 0, 0, 0);
                Oacc[1][et] = __builtin_amdgcn_mfma_f32_16x16x32_f16(pf[1][ks2], vf, Oacc[1][et], 0, 0, 0);
            }
        __builtin_amdgcn_s_setprio(0);
        __syncthreads();   // all PV vts reads + krot(nxt) writes done

        // ================= phase B =================
        if (ti + 1 < NTILES) {
            VBUILD();                         // vts(ti+1) from vv = LOAD(ti+1)
            if (ti + 2 < NTILES) LOAD((ti + 2) * 64);
        }
        __syncthreads();   // vts(ti+1) visible to all waves' PV next iter
    }

    // ---- epilogue ----
    float* ob = out + ((size_t)((b * L_ + l0) * H_ + h)) * E_;
#pragma unroll
    for (int set = 0; set < 2; ++set)
#pragma unroll
        for (int r = 0; r < 4; ++r) {
            float lr = __shfl(lrow[set], quad * 4 + r, 64);
            float inv = 1.0f / lr;
            int row = wv * 32 + set * 16 + quad * 4 + r;   // 0..255
#pragma unroll
            for (int et = 0; et < 4; ++et)
                ob[(size_t)row * (H_ * E_) + et * 16 + nn] = Oacc[set][et][r] * inv;
        }
}

extern "C" void kernel_launch(void* const* d_in, const int* in_sizes, int n_in,
                              void* d_out, int out_size, void* d_ws, size_t ws_size,
                              hipStream_t stream) {
    const float* qp = (const float*)d_in[0];
    const float* kp = (const float*)d_in[1];
    const float* vp = (const float*)d_in[2];
    const float* qo = (const float*)d_in[3];
    const float* qt = (const float*)d_in[4];
    const float* ko = (const float*)d_in[5];
    const float* kt = (const float*)d_in[6];
    float* out = (float*)d_out;

    qattn12<<<dim3(B_ * H_ * (L_ / QBLK)), dim3(NTH), 0, stream>>>(
        qp, kp, vp, qo, qt, ko, kt, out);
}